// Round 12
// baseline (1432.561 us; speedup 1.0000x reference)
//
#include <hip/hip_runtime.h>

typedef unsigned short u16;
typedef unsigned int u32;
typedef __attribute__((ext_vector_type(8))) short short8;
typedef __attribute__((ext_vector_type(2))) float f32x2;
typedef __attribute__((ext_vector_type(4))) float f32x4;
typedef __attribute__((ext_vector_type(16))) float f32x16;
typedef __attribute__((ext_vector_type(2))) unsigned int u32x2;
typedef __attribute__((ext_vector_type(4))) unsigned int u32x4;

#define AS1 __attribute__((address_space(1)))
#define AS3 __attribute__((address_space(3)))

__device__ __forceinline__ u16 f2bf(float f) {
  u32 u = __float_as_uint(f);
  u += 0x7FFFu + ((u >> 16) & 1u);
  return (u16)(u >> 16);
}

// packed f32x2 -> bf16x2 (RNE) HW op; elem0 = low 16 bits
__device__ __forceinline__ u32 cvt_pk_bf16(float lo, float hi) {
  u32 r;
  asm("v_cvt_pk_bf16_f32 %0, %1, %2" : "=v"(r) : "v"(lo), "v"(hi));
  return r;
}

// Pure-polynomial exact-GELU for |x| <= 1.5 (error < 3e-6 there), on f32x2
// pairs so the compiler can emit v_pk_fma_f32.
__device__ __forceinline__ f32x2 gelu_poly2(f32x2 x) {
  const f32x2 v = x * x;
  f32x2 p = __builtin_elementwise_fma(v, (f32x2)(-4.12267e-8f), (f32x2)(6.65969e-7f));
  p = __builtin_elementwise_fma(p, v, (f32x2)(-9.44466e-6f));
  p = __builtin_elementwise_fma(p, v, (f32x2)(1.15437e-4f));
  p = __builtin_elementwise_fma(p, v, (f32x2)(-1.1873282e-3f));
  p = __builtin_elementwise_fma(p, v, (f32x2)(9.973557e-3f));
  p = __builtin_elementwise_fma(p, v, (f32x2)(-6.649038e-2f));
  p = __builtin_elementwise_fma(p, v, (f32x2)(0.3989422804f));
  return x * __builtin_elementwise_fma(x, p, (f32x2)0.5f);
}

// Fallback for rare |x| > 1.5: A&S 7.1.26 erfc (|err|~1.5e-7), branch-free.
__device__ __forceinline__ float gelu_as(float x) {
  float ax = __builtin_fabsf(0.70710678118654752f * x);
  float t  = __builtin_amdgcn_rcpf(__builtin_fmaf(0.3275911f, ax, 1.0f));
  float p  = __builtin_fmaf(__builtin_fmaf(__builtin_fmaf(__builtin_fmaf(
               0.5307027145f, t, -0.7265760135f), t, 0.7107068705f), t,
               -0.142248368f), t, 0.127414796f);
  float e  = __expf(-(ax * ax));
  float h  = (p * t) * e;
  float phi = (x >= 0.0f) ? (1.0f - h) : h;
  return x * phi;
}

// ---- prep: one contiguous 140800-byte LDS image in ws, staged LINEARLY by
// main via global_load_lds; swizzled regions pre-apply the XOR involution.
// bytes [0,131072):       W1..W4 transposed [n][kp], kp holds k = kp^((n&7)<<3)
//                         (W1 k-padded 48->128, row k=48 = b1 bias feature)
// bytes [131072,139264):  W5T padded [n=0..31][kp], same pre-swizzle
// bytes [139264,140800):  384 f32, layers 2..4 bias in D-fragment order:
//                         [Lz][mb][hi][reg] = b[32mb + (r&3) + 8(r>>2) + 4hi]
__global__ void prep_weights(const float* __restrict__ W1, const float* __restrict__ b1,
                             const float* __restrict__ W2, const float* __restrict__ W3,
                             const float* __restrict__ W4, const float* __restrict__ W5,
                             const float* __restrict__ b2, const float* __restrict__ b3,
                             const float* __restrict__ b4, u16* __restrict__ ws) {
  int idx = blockIdx.x * 256 + threadIdx.x;
  if (idx < 65536) {
    int L = idx >> 14, rem = idx & 16383;
    int n = rem >> 7, kp = rem & 127;
    int k = kp ^ ((n & 7) << 3);        // pre-swizzle: dest kp holds source k
    float v;
    if (L == 0)      v = (k < 48) ? W1[k * 128 + n] : (k == 48 ? b1[n] : 0.f);
    else if (L == 1) v = W2[k * 128 + n];
    else if (L == 2) v = W3[k * 128 + n];
    else             v = W4[k * 128 + n];
    ws[idx] = f2bf(v);
  } else if (idx < 69632) {
    int i = idx - 65536;
    int n = i >> 7, kp = i & 127;
    int k = kp ^ ((n & 7) << 3);        // W5 pre-swizzled too (LDS-served)
    ws[idx] = f2bf((n < 4) ? W5[k * 4 + n] : 0.f);
  } else if (idx < 70016) {
    int t = idx - 69632;
    int Lz = t >> 7, rem = t & 127;
    int mb = rem >> 5, hi = (rem >> 4) & 1, r = rem & 15;
    const float* bl = (Lz == 0) ? b2 : (Lz == 1) ? b3 : b4;
    ((float*)ws)[34816 + t] = bl[mb * 32 + (r & 3) + 8 * (r >> 2) + 4 * hi];
  }
}

// GELU + repack one chunk's D (2 m-blocks, 32 f32/lane) into B-frags
// bnext[4c..4c+3] for the next layer. D rows: 32mb+(reg&3)+8(reg>>2)+4hi,
// col = sample = l31. B frag kk: k = 16kk + 8hi + j, col = l31.
// Half-exchange via permlane32_swap(first=P, second=Q):
//   first'[i>=32] = second[i-32] ; second'[i<32] = first[i+32]
//   => P' = {lo: own P, hi: partner Q} = b.x/b.y (rows +0..3 / +8..11)
//      Q' = {lo: partner P, hi: own Q} = b.z/b.w (rows +4..7 / +12..15)
// (matches R10's proven shfl+select table exactly; R11 had operands reversed)
__device__ __forceinline__ void gelu_pack(const f32x16& A0, const f32x16& A1,
                                          u32x4* bnext, int c, int hi) {
  float mx = 0.f;
  #pragma unroll
  for (int i = 0; i < 16; i += 2) {
    mx = __builtin_fmaxf(mx, __builtin_fmaxf(__builtin_fabsf(A0[i]),
                                             __builtin_fabsf(A0[i + 1])));
    mx = __builtin_fmaxf(mx, __builtin_fmaxf(__builtin_fabsf(A1[i]),
                                             __builtin_fabsf(A1[i + 1])));
  }
  const bool safe = !__any(mx > 1.5f);
  #pragma unroll
  for (int t2 = 0; t2 < 4; ++t2) {
    const f32x16& D = (t2 < 2) ? A0 : A1;
    const int g4 = 8 * (t2 & 1);          // reg-quad pair g,g+1 (g=2*(t2&1))
    float e[8];
    if (safe) {
      #pragma unroll
      for (int i = 0; i < 8; i += 2) {
        const f32x2 g = gelu_poly2((f32x2){D[g4 + i], D[g4 + i + 1]});
        e[i] = g.x; e[i + 1] = g.y;
      }
    } else {
      #pragma unroll
      for (int i = 0; i < 8; ++i) e[i] = gelu_as(D[g4 + i]);
    }
    const u32 P0 = cvt_pk_bf16(e[0], e[1]);
    const u32 P1 = cvt_pk_bf16(e[2], e[3]);
    const u32 Q0 = cvt_pk_bf16(e[4], e[5]);
    const u32 Q1 = cvt_pk_bf16(e[6], e[7]);
    const u32x2 r0 = __builtin_amdgcn_permlane32_swap(P0, Q0, false, false);
    const u32x2 r1 = __builtin_amdgcn_permlane32_swap(P1, Q1, false, false);
    u32x4 b;
    b.x = r0.x;   // lo: own P rows +0..3 ; hi: partner Q rows +8..11
    b.y = r1.x;
    b.z = r0.y;   // lo: partner P rows +4..7 ; hi: own Q rows +12..15
    b.w = r1.y;
    bnext[4 * c + t2] = b;
  }
}

// One 1024-thread block (16 waves) stages the FULL weight image into LDS once
// -> ONE barrier. Each wave independently runs 4 x 32-sample register-resident
// transposed-MFMA passes (fully unrolled; gathers hoisted into one batch).
__global__ __launch_bounds__(1024) void domino_main(
    const float* __restrict__ qp, const float* __restrict__ pts,
    const float* __restrict__ freqs, const float* __restrict__ b5,
    const int* __restrict__ mapping, const u16* __restrict__ wsW,
    float* __restrict__ out) {
  __shared__ alignas(16) char W[140800];
  const int tid = threadIdx.x;
  const int wid = tid >> 6;

  // ---- stage image linearly: 8 x 16KB chunks + 9728B tail ----
  {
    const char* src = (const char*)wsW;
    #pragma unroll
    for (int c = 0; c < 8; ++c)
      __builtin_amdgcn_global_load_lds(
          (const AS1 void*)(const void*)(src + c * 16384 + tid * 16),
          (AS3 void*)(void*)(W + c * 16384 + wid * 1024), 16, 0, 0);
    if (tid * 16 < 9728)   // lane-predicated tail; holes past image are unused
      __builtin_amdgcn_global_load_lds(
          (const AS1 void*)(const void*)(src + 131072 + tid * 16),
          (AS3 void*)(void*)(W + 131072 + wid * 1024), 16, 0, 0);
  }
  __syncthreads();   // the ONLY barrier: drains DMA; W read-only afterwards

  const int lane = tid & 63;
  const int l31  = lane & 31;
  const int hi   = lane >> 5;
  const int swl  = (l31 & 7) << 4;        // lane-constant row-XOR (row&7=l31&7)

  // lane needs 24 of the 48 features; phase-select sin/cos per half:
  // lo: sin j0-7,16-23 + cos j8-15 ; hi: cos j0-7,16-23 + sin j8-15
  const float PH = 1.57079632679489662f;
  const float ph_mid = hi ? 0.f : PH;
  const float ph_out = hi ? PH : 0.f;
  float fq[8];
  #pragma unroll
  for (int f = 0; f < 8; ++f) fq[f] = freqs[f];

  const int gw = blockIdx.x * 16 + wid;   // 0..8191

  // ---- hoisted gathers: ONE parallel latency exposure for all 4 iters ----
  int nbv[4];
  #pragma unroll
  for (int it = 0; it < 4; ++it)
    nbv[it] = mapping[(gw * 4 + it) * 32 + l31];
  float relv[4][3];
  #pragma unroll
  for (int it = 0; it < 4; ++it) {
    const int s  = (gw * 4 + it) * 32 + l31;
    const int mg = s >> 3;
    #pragma unroll
    for (int d = 0; d < 3; ++d)
      relv[it][d] = pts[nbv[it] * 3 + d] - qp[mg * 3 + d];
  }

  #pragma unroll
  for (int it = 0; it < 4; ++it) {
    const int wg = gw * 4 + it;           // 0..32767

    // ---- features, built directly in B-fragment layout ----
    float t[24];
    #pragma unroll
    for (int j = 0; j < 24; ++j) {
      const float a = __builtin_fmaf(relv[it][j % 3], fq[j / 3],
                                     (j >= 8 && j < 16) ? ph_mid : ph_out);
      t[j] = __sinf(a);
    }
    u32 pk[12];
    #pragma unroll
    for (int i = 0; i < 12; ++i) pk[i] = cvt_pk_bf16(t[2 * i], t[2 * i + 1]);

    u32x4 bcur[8];
    // k = 16kk + 8hi + j ; k<24: sin k ; 24<=k<48: cos(k-24) ; k=48: 1 ; else 0
    bcur[0] = hi ? (u32x4){pk[4], pk[5], pk[6], pk[7]}
                 : (u32x4){pk[0], pk[1], pk[2], pk[3]};
    bcur[1] = hi ? (u32x4){pk[0], pk[1], pk[2], pk[3]}
                 : (u32x4){pk[8], pk[9], pk[10], pk[11]};
    bcur[2] = hi ? (u32x4){pk[8], pk[9], pk[10], pk[11]}
                 : (u32x4){pk[4], pk[5], pk[6], pk[7]};
    bcur[3] = (u32x4){hi ? 0u : 0x3F80u, 0u, 0u, 0u}; // bias-feature 1.0 @k=48

    // ---- layer 1: K=64 (4 kk), acc init 0 (bias folded into W row 48) ----
    {
      u32x4 bnext[8];
      #pragma unroll
      for (int c = 0; c < 2; ++c) {
        f32x16 A0, A1;
        #pragma unroll
        for (int i = 0; i < 16; ++i) { A0[i] = 0.f; A1[i] = 0.f; }
        #pragma unroll
        for (int kk = 0; kk < 4; ++kk) {
          const short8 w0 = *(const short8*)(W + ((((2 * c) * 32 + l31) * 256 + kk * 32 + hi * 16) ^ swl));
          const short8 w1 = *(const short8*)(W + ((((2 * c + 1) * 32 + l31) * 256 + kk * 32 + hi * 16) ^ swl));
          const short8 bf = __builtin_bit_cast(short8, bcur[kk]);
          A0 = __builtin_amdgcn_mfma_f32_32x32x16_bf16(w0, bf, A0, 0, 0, 0);
          A1 = __builtin_amdgcn_mfma_f32_32x32x16_bf16(w1, bf, A1, 0, 0, 0);
        }
        gelu_pack(A0, A1, bnext, c, hi);
      }
      #pragma unroll
      for (int kk = 0; kk < 8; ++kk) bcur[kk] = bnext[kk];
    }

    // ---- layers 2..4: K=128 (8 kk), acc init = bias fragment (LDS) ----
    #pragma unroll
    for (int Lz = 0; Lz < 3; ++Lz) {
      const char* Wl = W + (Lz + 1) * 32768;
      const char* Bp = W + 139264 + Lz * 512;
      u32x4 bnext[8];
      #pragma unroll
      for (int c = 0; c < 2; ++c) {
        f32x16 A0, A1;
        #pragma unroll
        for (int q = 0; q < 4; ++q) {
          const f32x4 v0 = *(const f32x4*)(Bp + ((2 * c) * 2 + hi) * 64 + q * 16);
          const f32x4 v1 = *(const f32x4*)(Bp + ((2 * c + 1) * 2 + hi) * 64 + q * 16);
          #pragma unroll
          for (int e = 0; e < 4; ++e) { A0[q * 4 + e] = v0[e]; A1[q * 4 + e] = v1[e]; }
        }
        #pragma unroll
        for (int kk = 0; kk < 8; ++kk) {
          const short8 w0 = *(const short8*)(Wl + ((((2 * c) * 32 + l31) * 256 + kk * 32 + hi * 16) ^ swl));
          const short8 w1 = *(const short8*)(Wl + ((((2 * c + 1) * 32 + l31) * 256 + kk * 32 + hi * 16) ^ swl));
          const short8 bf = __builtin_bit_cast(short8, bcur[kk]);
          A0 = __builtin_amdgcn_mfma_f32_32x32x16_bf16(w0, bf, A0, 0, 0, 0);
          A1 = __builtin_amdgcn_mfma_f32_32x32x16_bf16(w1, bf, A1, 0, 0, 0);
        }
        gelu_pack(A0, A1, bnext, c, hi);
      }
      #pragma unroll
      for (int kk = 0; kk < 8; ++kk) bcur[kk] = bnext[kk];
    }

    // ---- layer 5: from LDS (swizzled like W1..W4) ----
    {
      f32x16 A5;
      #pragma unroll
      for (int i = 0; i < 16; ++i) A5[i] = 0.f;
      #pragma unroll
      for (int kk = 0; kk < 8; ++kk) {
        const short8 w = *(const short8*)(W + 131072 + ((l31 * 256 + kk * 32 + hi * 16) ^ swl));
        A5 = __builtin_amdgcn_mfma_f32_32x32x16_bf16(
            w, __builtin_bit_cast(short8, bcur[kk]), A5, 0, 0, 0);
      }
      // mean over the 8 neighbors = lanes 8q..8q+7 (lo half)
      float r0 = A5[0], r1 = A5[1], r2 = A5[2], r3 = A5[3];
      #pragma unroll
      for (int d = 1; d < 8; d <<= 1) {
        r0 += __shfl_xor(r0, d, 64);
        r1 += __shfl_xor(r1, d, 64);
        r2 += __shfl_xor(r2, d, 64);
        r3 += __shfl_xor(r3, d, 64);
      }
      if (hi == 0 && (l31 & 7) == 0) {
        const f32x4 b5v = *(const f32x4*)b5;
        f32x4 o;
        o.x = __builtin_fmaf(0.125f, r0, b5v.x);
        o.y = __builtin_fmaf(0.125f, r1, b5v.y);
        o.z = __builtin_fmaf(0.125f, r2, b5v.z);
        o.w = __builtin_fmaf(0.125f, r3, b5v.w);
        *(f32x4*)(out + (wg * 4 + (l31 >> 3)) * 4) = o;
      }
    }
  }
}

extern "C" void kernel_launch(void* const* d_in, const int* in_sizes, int n_in,
                              void* d_out, int out_size, void* d_ws, size_t ws_size,
                              hipStream_t stream) {
  const float* qp      = (const float*)d_in[0];
  const float* pts     = (const float*)d_in[1];
  const float* freqs   = (const float*)d_in[2];
  const float* W1      = (const float*)d_in[3];
  const float* b1      = (const float*)d_in[4];
  const float* W2      = (const float*)d_in[5];
  const float* b2      = (const float*)d_in[6];
  const float* W3      = (const float*)d_in[7];
  const float* b3      = (const float*)d_in[8];
  const float* W4      = (const float*)d_in[9];
  const float* b4      = (const float*)d_in[10];
  const float* W5      = (const float*)d_in[11];
  const float* b5      = (const float*)d_in[12];
  const int*   mapping = (const int*)d_in[13];
  u16* ws = (u16*)d_ws;
  float* out = (float*)d_out;

  prep_weights<<<dim3(274), dim3(256), 0, stream>>>(
      W1, b1, W2, W3, W4, W5, b2, b3, b4, ws);
  // 512 blocks x 16 waves x 4 iters x 32 samples = 1,048,576 rows
  domino_main<<<dim3(512), dim3(1024), 0, stream>>>(
      qp, pts, freqs, b5, mapping, ws, out);
}

// Round 13
// 232.113 us; speedup vs baseline: 6.1718x; 6.1718x over previous
//
#include <hip/hip_runtime.h>

typedef unsigned short u16;
typedef unsigned int u32;
typedef __attribute__((ext_vector_type(8))) short short8;
typedef __attribute__((ext_vector_type(2))) float f32x2;
typedef __attribute__((ext_vector_type(4))) float f32x4;
typedef __attribute__((ext_vector_type(16))) float f32x16;
typedef __attribute__((ext_vector_type(2))) unsigned int u32x2;
typedef __attribute__((ext_vector_type(4))) unsigned int u32x4;

#define AS1 __attribute__((address_space(1)))
#define AS3 __attribute__((address_space(3)))

__device__ __forceinline__ u16 f2bf(float f) {
  u32 u = __float_as_uint(f);
  u += 0x7FFFu + ((u >> 16) & 1u);
  return (u16)(u >> 16);
}

// packed f32x2 -> bf16x2 (RNE) HW op; elem0 = low 16 bits
__device__ __forceinline__ u32 cvt_pk_bf16(float lo, float hi) {
  u32 r;
  asm("v_cvt_pk_bf16_f32 %0, %1, %2" : "=v"(r) : "v"(lo), "v"(hi));
  return r;
}

// Pure-polynomial exact-GELU for |x| <= 1.5 (error < 3e-6 there), on f32x2
// pairs so the compiler can emit v_pk_fma_f32.
__device__ __forceinline__ f32x2 gelu_poly2(f32x2 x) {
  const f32x2 v = x * x;
  f32x2 p = __builtin_elementwise_fma(v, (f32x2)(-4.12267e-8f), (f32x2)(6.65969e-7f));
  p = __builtin_elementwise_fma(p, v, (f32x2)(-9.44466e-6f));
  p = __builtin_elementwise_fma(p, v, (f32x2)(1.15437e-4f));
  p = __builtin_elementwise_fma(p, v, (f32x2)(-1.1873282e-3f));
  p = __builtin_elementwise_fma(p, v, (f32x2)(9.973557e-3f));
  p = __builtin_elementwise_fma(p, v, (f32x2)(-6.649038e-2f));
  p = __builtin_elementwise_fma(p, v, (f32x2)(0.3989422804f));
  return x * __builtin_elementwise_fma(x, p, (f32x2)0.5f);
}

// Fallback for rare |x| > 1.5: A&S 7.1.26 erfc (|err|~1.5e-7), branch-free.
__device__ __forceinline__ float gelu_as(float x) {
  float ax = __builtin_fabsf(0.70710678118654752f * x);
  float t  = __builtin_amdgcn_rcpf(__builtin_fmaf(0.3275911f, ax, 1.0f));
  float p  = __builtin_fmaf(__builtin_fmaf(__builtin_fmaf(__builtin_fmaf(
               0.5307027145f, t, -0.7265760135f), t, 0.7107068705f), t,
               -0.142248368f), t, 0.127414796f);
  float e  = __expf(-(ax * ax));
  float h  = (p * t) * e;
  float phi = (x >= 0.0f) ? (1.0f - h) : h;
  return x * phi;
}

// ---- prep: one contiguous 140800-byte LDS image in ws, staged LINEARLY by
// main via global_load_lds; swizzled regions pre-apply the XOR involution.
// bytes [0,131072):       W1..W4 transposed [n][kp], kp holds k = kp^((n&7)<<3)
//                         (W1 k-padded 48->128, row k=48 = b1 bias feature)
// bytes [131072,139264):  W5T padded [n=0..31][kp], same pre-swizzle
// bytes [139264,140800):  384 f32, layers 2..4 bias in D-fragment order:
//                         [Lz][mb][hi][reg] = b[32mb + (r&3) + 8(r>>2) + 4hi]
__global__ void prep_weights(const float* __restrict__ W1, const float* __restrict__ b1,
                             const float* __restrict__ W2, const float* __restrict__ W3,
                             const float* __restrict__ W4, const float* __restrict__ W5,
                             const float* __restrict__ b2, const float* __restrict__ b3,
                             const float* __restrict__ b4, u16* __restrict__ ws) {
  int idx = blockIdx.x * 256 + threadIdx.x;
  if (idx < 65536) {
    int L = idx >> 14, rem = idx & 16383;
    int n = rem >> 7, kp = rem & 127;
    int k = kp ^ ((n & 7) << 3);        // pre-swizzle: dest kp holds source k
    float v;
    if (L == 0)      v = (k < 48) ? W1[k * 128 + n] : (k == 48 ? b1[n] : 0.f);
    else if (L == 1) v = W2[k * 128 + n];
    else if (L == 2) v = W3[k * 128 + n];
    else             v = W4[k * 128 + n];
    ws[idx] = f2bf(v);
  } else if (idx < 69632) {
    int i = idx - 65536;
    int n = i >> 7, kp = i & 127;
    int k = kp ^ ((n & 7) << 3);        // W5 pre-swizzled too (LDS-served)
    ws[idx] = f2bf((n < 4) ? W5[k * 4 + n] : 0.f);
  } else if (idx < 70016) {
    int t = idx - 69632;
    int Lz = t >> 7, rem = t & 127;
    int mb = rem >> 5, hi = (rem >> 4) & 1, r = rem & 15;
    const float* bl = (Lz == 0) ? b2 : (Lz == 1) ? b3 : b4;
    ((float*)ws)[34816 + t] = bl[mb * 32 + (r & 3) + 8 * (r >> 2) + 4 * hi];
  }
}

// GELU + repack one chunk's D (2 m-blocks, 32 f32/lane) into B-frags
// bnext[4c..4c+3] for the next layer. D rows: 32mb+(reg&3)+8(reg>>2)+4hi,
// col = sample = l31. B frag kk: k = 16kk + 8hi + j, col = l31.
// Half-exchange via permlane32_swap(first=P, second=Q)  [VERIFIED in R12]:
//   first'[i>=32] = second[i-32] ; second'[i<32] = first[i+32]
//   => P' = {lo: own P, hi: partner Q} = b.x/b.y (rows +0..3 / +8..11)
//      Q' = {lo: partner P, hi: own Q} = b.z/b.w (rows +4..7 / +12..15)
__device__ __forceinline__ void gelu_pack(const f32x16& A0, const f32x16& A1,
                                          u32x4* bnext, int c, int hi) {
  float mx = 0.f;
  #pragma unroll
  for (int i = 0; i < 16; i += 2) {
    mx = __builtin_fmaxf(mx, __builtin_fmaxf(__builtin_fabsf(A0[i]),
                                             __builtin_fabsf(A0[i + 1])));
    mx = __builtin_fmaxf(mx, __builtin_fmaxf(__builtin_fabsf(A1[i]),
                                             __builtin_fabsf(A1[i + 1])));
  }
  const bool safe = !__any(mx > 1.5f);
  #pragma unroll
  for (int t2 = 0; t2 < 4; ++t2) {
    const f32x16& D = (t2 < 2) ? A0 : A1;
    const int g4 = 8 * (t2 & 1);          // reg-quad pair g,g+1 (g=2*(t2&1))
    float e[8];
    if (safe) {
      #pragma unroll
      for (int i = 0; i < 8; i += 2) {
        const f32x2 g = gelu_poly2((f32x2){D[g4 + i], D[g4 + i + 1]});
        e[i] = g.x; e[i + 1] = g.y;
      }
    } else {
      #pragma unroll
      for (int i = 0; i < 8; ++i) e[i] = gelu_as(D[g4 + i]);
    }
    const u32 P0 = cvt_pk_bf16(e[0], e[1]);
    const u32 P1 = cvt_pk_bf16(e[2], e[3]);
    const u32 Q0 = cvt_pk_bf16(e[4], e[5]);
    const u32 Q1 = cvt_pk_bf16(e[6], e[7]);
    const u32x2 r0 = __builtin_amdgcn_permlane32_swap(P0, Q0, false, false);
    const u32x2 r1 = __builtin_amdgcn_permlane32_swap(P1, Q1, false, false);
    u32x4 b;
    b.x = r0.x;   // lo: own P rows +0..3 ; hi: partner Q rows +8..11
    b.y = r1.x;
    b.z = r0.y;   // lo: partner P rows +4..7 ; hi: own Q rows +12..15
    b.w = r1.y;
    bnext[4 * c + t2] = b;
  }
}

// One 1024-thread block (16 waves) stages the FULL weight image into LDS once
// -> ONE barrier. Each wave independently runs 4 x 32-sample register-resident
// transposed-MFMA passes. ROLLED it-loop + per-iteration gathers (R10 proven):
// the R12 unroll+hoist caused a 4.7GB scratch-spill regression.
__global__ __launch_bounds__(1024) void domino_main(
    const float* __restrict__ qp, const float* __restrict__ pts,
    const float* __restrict__ freqs, const float* __restrict__ b5,
    const int* __restrict__ mapping, const u16* __restrict__ wsW,
    float* __restrict__ out) {
  __shared__ alignas(16) char W[140800];
  const int tid = threadIdx.x;
  const int wid = tid >> 6;

  // ---- stage image linearly: 8 x 16KB chunks + 9728B tail ----
  {
    const char* src = (const char*)wsW;
    #pragma unroll
    for (int c = 0; c < 8; ++c)
      __builtin_amdgcn_global_load_lds(
          (const AS1 void*)(const void*)(src + c * 16384 + tid * 16),
          (AS3 void*)(void*)(W + c * 16384 + wid * 1024), 16, 0, 0);
    if (tid * 16 < 9728)   // lane-predicated tail; holes past image are unused
      __builtin_amdgcn_global_load_lds(
          (const AS1 void*)(const void*)(src + 131072 + tid * 16),
          (AS3 void*)(void*)(W + 131072 + wid * 1024), 16, 0, 0);
  }
  __syncthreads();   // the ONLY barrier: drains DMA; W read-only afterwards

  const int lane = tid & 63;
  const int l31  = lane & 31;
  const int hi   = lane >> 5;
  const int swl  = (l31 & 7) << 4;        // lane-constant row-XOR (row&7=l31&7)

  // lane needs 24 of the 48 features; phase-select sin/cos per half:
  // lo: sin j0-7,16-23 + cos j8-15 ; hi: cos j0-7,16-23 + sin j8-15
  const float PH = 1.57079632679489662f;
  const float ph_mid = hi ? 0.f : PH;
  const float ph_out = hi ? PH : 0.f;
  float fq[8];
  #pragma unroll
  for (int f = 0; f < 8; ++f) fq[f] = freqs[f];

  const int gw = blockIdx.x * 16 + wid;   // 0..8191

  for (int it = 0; it < 4; ++it) {        // ROLLED: avoids live-range blowup
    const int wg = gw * 4 + it;           // 0..32767

    // ---- per-iteration gather + features (B-fragment layout) ----
    const int s  = wg * 32 + l31;         // sample id (lo/hi duplicate)
    const int nb = mapping[s];
    const int mg = s >> 3;
    float rel[3];
    #pragma unroll
    for (int d = 0; d < 3; ++d) rel[d] = pts[nb * 3 + d] - qp[mg * 3 + d];
    float t[24];
    #pragma unroll
    for (int j = 0; j < 24; ++j) {
      const float a = __builtin_fmaf(rel[j % 3], fq[j / 3],
                                     (j >= 8 && j < 16) ? ph_mid : ph_out);
      t[j] = __sinf(a);
    }
    u32 pk[12];
    #pragma unroll
    for (int i = 0; i < 12; ++i) pk[i] = cvt_pk_bf16(t[2 * i], t[2 * i + 1]);

    u32x4 bcur[8];
    // k = 16kk + 8hi + j ; k<24: sin k ; 24<=k<48: cos(k-24) ; k=48: 1 ; else 0
    bcur[0] = hi ? (u32x4){pk[4], pk[5], pk[6], pk[7]}
                 : (u32x4){pk[0], pk[1], pk[2], pk[3]};
    bcur[1] = hi ? (u32x4){pk[0], pk[1], pk[2], pk[3]}
                 : (u32x4){pk[8], pk[9], pk[10], pk[11]};
    bcur[2] = hi ? (u32x4){pk[8], pk[9], pk[10], pk[11]}
                 : (u32x4){pk[4], pk[5], pk[6], pk[7]};
    bcur[3] = (u32x4){hi ? 0u : 0x3F80u, 0u, 0u, 0u}; // bias-feature 1.0 @k=48

    // ---- layer 1: K=64 (4 kk), acc init 0 (bias folded into W row 48) ----
    {
      u32x4 bnext[8];
      #pragma unroll
      for (int c = 0; c < 2; ++c) {
        f32x16 A0, A1;
        #pragma unroll
        for (int i = 0; i < 16; ++i) { A0[i] = 0.f; A1[i] = 0.f; }
        #pragma unroll
        for (int kk = 0; kk < 4; ++kk) {
          const short8 w0 = *(const short8*)(W + ((((2 * c) * 32 + l31) * 256 + kk * 32 + hi * 16) ^ swl));
          const short8 w1 = *(const short8*)(W + ((((2 * c + 1) * 32 + l31) * 256 + kk * 32 + hi * 16) ^ swl));
          const short8 bf = __builtin_bit_cast(short8, bcur[kk]);
          A0 = __builtin_amdgcn_mfma_f32_32x32x16_bf16(w0, bf, A0, 0, 0, 0);
          A1 = __builtin_amdgcn_mfma_f32_32x32x16_bf16(w1, bf, A1, 0, 0, 0);
        }
        gelu_pack(A0, A1, bnext, c, hi);
      }
      #pragma unroll
      for (int kk = 0; kk < 8; ++kk) bcur[kk] = bnext[kk];
    }

    // ---- layers 2..4: K=128 (8 kk), acc init = bias fragment (LDS) ----
    #pragma unroll
    for (int Lz = 0; Lz < 3; ++Lz) {
      const char* Wl = W + (Lz + 1) * 32768;
      const char* Bp = W + 139264 + Lz * 512;
      u32x4 bnext[8];
      #pragma unroll
      for (int c = 0; c < 2; ++c) {
        f32x16 A0, A1;
        #pragma unroll
        for (int q = 0; q < 4; ++q) {
          const f32x4 v0 = *(const f32x4*)(Bp + ((2 * c) * 2 + hi) * 64 + q * 16);
          const f32x4 v1 = *(const f32x4*)(Bp + ((2 * c + 1) * 2 + hi) * 64 + q * 16);
          #pragma unroll
          for (int e = 0; e < 4; ++e) { A0[q * 4 + e] = v0[e]; A1[q * 4 + e] = v1[e]; }
        }
        #pragma unroll
        for (int kk = 0; kk < 8; ++kk) {
          const short8 w0 = *(const short8*)(Wl + ((((2 * c) * 32 + l31) * 256 + kk * 32 + hi * 16) ^ swl));
          const short8 w1 = *(const short8*)(Wl + ((((2 * c + 1) * 32 + l31) * 256 + kk * 32 + hi * 16) ^ swl));
          const short8 bf = __builtin_bit_cast(short8, bcur[kk]);
          A0 = __builtin_amdgcn_mfma_f32_32x32x16_bf16(w0, bf, A0, 0, 0, 0);
          A1 = __builtin_amdgcn_mfma_f32_32x32x16_bf16(w1, bf, A1, 0, 0, 0);
        }
        gelu_pack(A0, A1, bnext, c, hi);
      }
      #pragma unroll
      for (int kk = 0; kk < 8; ++kk) bcur[kk] = bnext[kk];
    }

    // ---- layer 5: from LDS (swizzled like W1..W4) ----
    {
      f32x16 A5;
      #pragma unroll
      for (int i = 0; i < 16; ++i) A5[i] = 0.f;
      #pragma unroll
      for (int kk = 0; kk < 8; ++kk) {
        const short8 w = *(const short8*)(W + 131072 + ((l31 * 256 + kk * 32 + hi * 16) ^ swl));
        A5 = __builtin_amdgcn_mfma_f32_32x32x16_bf16(
            w, __builtin_bit_cast(short8, bcur[kk]), A5, 0, 0, 0);
      }
      // mean over the 8 neighbors = lanes 8q..8q+7 (lo half)
      float r0 = A5[0], r1 = A5[1], r2 = A5[2], r3 = A5[3];
      #pragma unroll
      for (int d = 1; d < 8; d <<= 1) {
        r0 += __shfl_xor(r0, d, 64);
        r1 += __shfl_xor(r1, d, 64);
        r2 += __shfl_xor(r2, d, 64);
        r3 += __shfl_xor(r3, d, 64);
      }
      if (hi == 0 && (l31 & 7) == 0) {
        const f32x4 b5v = *(const f32x4*)b5;
        f32x4 o;
        o.x = __builtin_fmaf(0.125f, r0, b5v.x);
        o.y = __builtin_fmaf(0.125f, r1, b5v.y);
        o.z = __builtin_fmaf(0.125f, r2, b5v.z);
        o.w = __builtin_fmaf(0.125f, r3, b5v.w);
        *(f32x4*)(out + (wg * 4 + (l31 >> 3)) * 4) = o;
      }
    }
  }
}

extern "C" void kernel_launch(void* const* d_in, const int* in_sizes, int n_in,
                              void* d_out, int out_size, void* d_ws, size_t ws_size,
                              hipStream_t stream) {
  const float* qp      = (const float*)d_in[0];
  const float* pts     = (const float*)d_in[1];
  const float* freqs   = (const float*)d_in[2];
  const float* W1      = (const float*)d_in[3];
  const float* b1      = (const float*)d_in[4];
  const float* W2      = (const float*)d_in[5];
  const float* b2      = (const float*)d_in[6];
  const float* W3      = (const float*)d_in[7];
  const float* b3      = (const float*)d_in[8];
  const float* W4      = (const float*)d_in[9];
  const float* b4      = (const float*)d_in[10];
  const float* W5      = (const float*)d_in[11];
  const float* b5      = (const float*)d_in[12];
  const int*   mapping = (const int*)d_in[13];
  u16* ws = (u16*)d_ws;
  float* out = (float*)d_out;

  prep_weights<<<dim3(274), dim3(256), 0, stream>>>(
      W1, b1, W2, W3, W4, W5, b2, b3, b4, ws);
  // 512 blocks x 16 waves x 4 iters x 32 samples = 1,048,576 rows
  domino_main<<<dim3(512), dim3(1024), 0, stream>>>(
      qp, pts, freqs, b5, mapping, ws, out);
}